// Round 5
// baseline (294.864 us; speedup 1.0000x reference)
//
#include <hip/hip_runtime.h>
#include <hip/hip_bf16.h>

// GraphFeatureExtractor: B=64, N=64, T=16, D=512
// out = person_features with [:, :, 15, :] replaced by 2-layer ST-GCN result.
//
// Round 7: kernel bodies identical to round-6 (verified). Only copy placement
// changed. Root cause found in round-6 post-mortem: copy-role blocks inside
// k_agg reserve the agg kernel's full 51KB static LDS (allocation is
// unconditional), capping copy backfill at 3 blocks/CU -> low copy BW in agg
// stages. Fix: copy lives ONLY in stages whose LDS footprint permits high
// occupancy:
//   S1 agg1+prep  : no copy        (pure compute, ~5us)
//   S2 gemm1      : 1152 groups    (12.3KB LDS -> 13 blocks/CU)
//   S3 agg2       : no copy
//   S4 gemm2      : 1152 groups
//   S5 norm       : 1792 groups    (0 LDS -> full occupancy)
// Copy unit = one (b,n) 16-row group with wave-uniform t=15 skip (norm writes
// those rows; zero races; [0,1152)+[1152,2304)+[2304,4096) covers all 4096).

typedef __attribute__((ext_vector_type(8))) short short8;
typedef __attribute__((ext_vector_type(4))) float v4f;

#define DIST_THRESH 150.0f
#define ROW_EPS 1e-6f
#define BN_EPS 1e-5f

__device__ __forceinline__ ushort f2bf(float f) {
  union { __hip_bfloat16 h; ushort u; } cv;
  cv.h = __float2bfloat16(f);
  return cv.u;
}

// ---------------- copy unit: one (b,n) group = 16 rows x 512 f = 8 KB -------
// Copies rows t=0..14 only. Group g covers float4 [g*2048, (g+1)*2048).
// Thread t handles idx t + 256k, k=0..7; k=7 is row 14 for t<128 (copied)
// and row 15 for t>=128 (skipped) -- wave-uniform predicate, dense otherwise.
__device__ __forceinline__ void copy_group(const float4* __restrict__ in,
                                           float4* __restrict__ out,
                                           int g, int t) {
  size_t base = (size_t)g * 2048 + t;
  bool last = (t < 128);  // wave-uniform (waves 0-1 true, waves 2-3 false)
  float4 r[8];
#pragma unroll
  for (int k = 0; k < 7; ++k) r[k] = in[base + (size_t)k * 256];
  if (last) r[7] = in[base + 7 * 256];
#pragma unroll
  for (int k = 0; k < 7; ++k) out[base + (size_t)k * 256] = r[k];
  if (last) out[base + 7 * 256] = r[7];
}

// ---------------- weight -> bf16 (float4 granular) --------------------------
__device__ __forceinline__ void prep_unit(int i4, const float* __restrict__ w1,
                                          const float* __restrict__ w2,
                                          ushort* __restrict__ wb) {
  float4 v = (i4 < 65536) ? *(const float4*)&w1[(size_t)i4 * 4]
                          : *(const float4*)&w2[(size_t)(i4 - 65536) * 4];
  ushort4 o;
  o.x = f2bf(v.x);
  o.y = f2bf(v.y);
  o.z = f2bf(v.z);
  o.w = f2bf(v.w);
  *(ushort4*)&wb[(size_t)i4 * 4] = o;
}

// ---------------- aggregation (+inline adjacency, +optional BN/relu on X) ----
// Z[b][m][c] = sum_n A_norm[b][n][m] * X[b][n][c]
// block roles: [0,256) agg; [256,grid) weight-prep (stage 1 only).
__global__ __launch_bounds__(256) void k_agg(const float* __restrict__ Xbase,
                                             int rowStride,
                                             const float* __restrict__ bb,
                                             const float* __restrict__ stats,  // [sum(512)|sumsq(512)]
                                             const float* __restrict__ g,
                                             const float* __restrict__ beta,
                                             int applyBN,
                                             ushort* __restrict__ Z,
                                             const float* __restrict__ w1,
                                             const float* __restrict__ w2,
                                             ushort* __restrict__ wb,
                                             float* __restrict__ statsZ) {
  int id = blockIdx.x;
  int t = threadIdx.x;

  if (id >= 256) {  // weight prep role (stage 1 only): 2 units per block
    int pb = id - 256;
#pragma unroll
    for (int u = 0; u < 2; ++u) prep_unit((pb * 2 + u) * 256 + t, w1, w2, wb);
    if (pb == 0) {
      for (int i = t; i < 512; i += 256)
        ((float4*)statsZ)[i] = make_float4(0.f, 0.f, 0.f, 0.f);
    }
    return;
  }

  int b = id >> 2;          // 64 batches
  int c0 = (id & 3) << 7;   // 4 column tiles of 128
  __shared__ float Xs[64][128];  // 32 KB
  __shared__ float As[64][64];   // 16 KB  (A_norm[b], [n][m])
  __shared__ float cxs[64], cys[64];
  __shared__ float scaleS[128], shiftS[128];
  __shared__ float rsum[64][4];
  __shared__ float invr[64];

  if (t < 64) {
    float4 v = *(const float4*)&bb[(size_t)(b * 64 + t) * 4];
    cxs[t] = v.x + 0.5f * v.z;
    cys[t] = v.y + 0.5f * v.w;
  }
  if (applyBN && t < 32) {
    int c = t * 4;  // local column in tile
    float4 sm = *(const float4*)&stats[c0 + c];
    float4 sq = *(const float4*)&stats[512 + c0 + c];
    float4 gg = *(const float4*)&g[c0 + c];
    float4 bt = *(const float4*)&beta[c0 + c];
    const float inv = 1.0f / 4096.0f;
    float mean, var, sc;
    mean = sm.x * inv; var = sq.x * inv - mean * mean; sc = gg.x * rsqrtf(var + BN_EPS);
    scaleS[c] = sc; shiftS[c] = bt.x - mean * sc;
    mean = sm.y * inv; var = sq.y * inv - mean * mean; sc = gg.y * rsqrtf(var + BN_EPS);
    scaleS[c + 1] = sc; shiftS[c + 1] = bt.y - mean * sc;
    mean = sm.z * inv; var = sq.z * inv - mean * mean; sc = gg.z * rsqrtf(var + BN_EPS);
    scaleS[c + 2] = sc; shiftS[c + 2] = bt.z - mean * sc;
    mean = sm.w * inv; var = sq.w * inv - mean * mean; sc = gg.w * rsqrtf(var + BN_EPS);
    scaleS[c + 3] = sc; shiftS[c + 3] = bt.w - mean * sc;
  }
  __syncthreads();

  // parallel adjacency: thread t owns row an = t>>2, 16-col segment aq = t&3
  int an = t >> 2, aq = t & 3;
  float av[16];
  {
    float mycx = cxs[an], mycy = cys[an];
    float ps = 0.f;
#pragma unroll
    for (int j = 0; j < 16; ++j) {
      int m = aq * 16 + j;
      float dx = mycx - cxs[m], dy = mycy - cys[m];
      float d = sqrtf(dx * dx + dy * dy);
      float a = (m == an) ? 1.0f : ((d < DIST_THRESH) ? 1.0f : 0.0f);
      av[j] = a;
      ps += a;
    }
    rsum[an][aq] = ps;
  }

  // X tile load (+BN/relu for layer 2) — overlapped with A-build
  const float* xb = Xbase + (size_t)b * 64 * rowStride;
  for (int i = t; i < 2048; i += 256) {  // 64 rows x 32 float4
    int n = i >> 5, c4 = (i & 31) << 2;
    float4 x = *(const float4*)&xb[(size_t)n * rowStride + c0 + c4];
    if (applyBN) {
      x.x = fmaxf(x.x * scaleS[c4] + shiftS[c4], 0.f);
      x.y = fmaxf(x.y * scaleS[c4 + 1] + shiftS[c4 + 1], 0.f);
      x.z = fmaxf(x.z * scaleS[c4 + 2] + shiftS[c4 + 2], 0.f);
      x.w = fmaxf(x.w * scaleS[c4 + 3] + shiftS[c4 + 3], 0.f);
    }
    *(float4*)&Xs[n][c4] = x;
  }
  __syncthreads();

  if (t < 64)
    invr[t] = 1.0f / (rsum[t][0] + rsum[t][1] + rsum[t][2] + rsum[t][3] + ROW_EPS);
  __syncthreads();

  {
    float iv = invr[an];
#pragma unroll
    for (int j = 0; j < 16; ++j) As[an][aq * 16 + j] = av[j] * iv;
  }
  __syncthreads();

  int c4 = (t & 31) << 2;   // column group (4 floats)
  int m0 = (t >> 5) << 3;   // 8 output nodes per thread
  float4 acc[8];
#pragma unroll
  for (int i = 0; i < 8; ++i) acc[i] = make_float4(0.f, 0.f, 0.f, 0.f);

  for (int n = 0; n < 64; ++n) {
    float4 x = *(const float4*)&Xs[n][c4];
    float4 a0 = *(const float4*)&As[n][m0];
    float4 a1 = *(const float4*)&As[n][m0 + 4];
    float as[8] = {a0.x, a0.y, a0.z, a0.w, a1.x, a1.y, a1.z, a1.w};
#pragma unroll
    for (int i = 0; i < 8; ++i) {
      acc[i].x = fmaf(as[i], x.x, acc[i].x);
      acc[i].y = fmaf(as[i], x.y, acc[i].y);
      acc[i].z = fmaf(as[i], x.z, acc[i].z);
      acc[i].w = fmaf(as[i], x.w, acc[i].w);
    }
  }

  size_t zbase = (size_t)b * 64 * 512 + c0 + c4;
#pragma unroll
  for (int i = 0; i < 8; ++i) {
    int m = m0 + i;
    ushort4 zz;
    zz.x = f2bf(acc[i].x);
    zz.y = f2bf(acc[i].y);
    zz.z = f2bf(acc[i].z);
    zz.w = f2bf(acc[i].w);
    *(ushort4*)&Z[zbase + (size_t)m * 512] = zz;
  }
}

// ---------------- GEMM: Y[r][o] = sum_c Z[r][c]*W[o][c] + bias[o] ------------
// tile 64(M) x 64(N), BK=32, 256 threads = 4 waves, each wave 16 rows x 64 cols
// block roles: [0,512) gemm; [512, grid) copy groups starting at copyBase.
// (copy blocks here inherit only ~12.3KB LDS -> 13 blocks/CU -> good copy BW)
__global__ __launch_bounds__(256) void k_gemm(const ushort* __restrict__ Z,
                                              const ushort* __restrict__ W,
                                              const float* __restrict__ bias,
                                              float* __restrict__ Y,
                                              float* __restrict__ sum,
                                              float* __restrict__ sumsq,
                                              const float4* __restrict__ in4,
                                              float4* __restrict__ out4,
                                              int copyBase) {
  int id = blockIdx.x;
  int t = threadIdx.x;
  if (id >= 512) {  // copy role
    copy_group(in4, out4, copyBase + (id - 512), t);
    return;
  }

  __shared__ __align__(16) ushort Zs[64 * 40];  // pad 32->40
  __shared__ __align__(16) ushort Ws[64 * 40];
  __shared__ float redS[4][64], redQ[4][64];

  int r0 = (id >> 3) << 6;  // 64 row tiles
  int o0 = (id & 7) << 6;   // 8 col tiles
  int wv = t >> 6, lane = t & 63;
  int m = lane & 15, q = lane >> 4;

  v4f acc[4];
#pragma unroll
  for (int nf = 0; nf < 4; ++nf) acc[nf] = (v4f){0.f, 0.f, 0.f, 0.f};

  int srow = t >> 2, scg = (t & 3) << 3;  // staging: row 0..63, 8-bf16 groups
  const ushort* zp = &Z[(size_t)(r0 + srow) * 512 + scg];
  const ushort* wp = &W[(size_t)(o0 + srow) * 512 + scg];

  // prefetch first tile
  uint4 zv = *(const uint4*)zp;
  uint4 wvv = *(const uint4*)wp;

  for (int ks = 0; ks < 16; ++ks) {
    __syncthreads();
    *(uint4*)&Zs[srow * 40 + scg] = zv;
    *(uint4*)&Ws[srow * 40 + scg] = wvv;
    __syncthreads();

    if (ks < 15) {  // prefetch next tile; latency hides under ds_read+MFMA
      zv = *(const uint4*)(zp + (ks + 1) * 32);
      wvv = *(const uint4*)(wp + (ks + 1) * 32);
    }

    short8 a = *(const short8*)&Zs[(wv * 16 + m) * 40 + q * 8];
#pragma unroll
    for (int nf = 0; nf < 4; ++nf) {
      short8 bfr = *(const short8*)&Ws[(nf * 16 + m) * 40 + q * 8];
      acc[nf] = __builtin_amdgcn_mfma_f32_16x16x32_bf16(a, bfr, acc[nf], 0, 0, 0);
    }
  }

  // epilogue: bias, store Y fp32, per-column BN partial sums
#pragma unroll
  for (int nf = 0; nf < 4; ++nf) {
    int col = o0 + nf * 16 + m;
    float bv = bias[col];
    float s = 0.f, s2 = 0.f;
#pragma unroll
    for (int reg = 0; reg < 4; ++reg) {
      int row = r0 + wv * 16 + q * 4 + reg;
      float y = acc[nf][reg] + bv;
      Y[(size_t)row * 512 + col] = y;
      s += y;
      s2 += y * y;
    }
    s += __shfl_xor(s, 16);
    s += __shfl_xor(s, 32);
    s2 += __shfl_xor(s2, 16);
    s2 += __shfl_xor(s2, 32);
    if (q == 0) {
      redS[wv][nf * 16 + m] = s;
      redQ[wv][nf * 16 + m] = s2;
    }
  }
  __syncthreads();
  if (t < 64) {
    float s = redS[0][t] + redS[1][t] + redS[2][t] + redS[3][t];
    float s2 = redQ[0][t] + redQ[1][t] + redQ[2][t] + redQ[3][t];
    atomicAdd(&sum[o0 + t], s);
    atomicAdd(&sumsq[o0 + t], s2);
  }
}

// ---------------- final BN + relu -> t=15 slice of d_out ---------------------
// block roles: [0,2048) norm; [2048, grid) copy groups (no LDS -> full occ.)
__global__ __launch_bounds__(256) void k_norm(const float* __restrict__ Y,
                                              const float* __restrict__ sum,
                                              const float* __restrict__ sumsq,
                                              const float* __restrict__ g,
                                              const float* __restrict__ beta,
                                              float* __restrict__ out,
                                              const float4* __restrict__ in4,
                                              float4* __restrict__ out4,
                                              int copyBase) {
  int id = blockIdx.x;
  int t = threadIdx.x;
  if (id >= 2048) {  // copy role (copy never writes t=15 rows -> no race)
    copy_group(in4, out4, copyBase + (id - 2048), t);
    return;
  }
  int idx = id * 256 + t;  // 524288 float4 groups
  int o = (idx & 127) << 2;
  int r = idx >> 7;
  float4 y = *(const float4*)&Y[(size_t)r * 512 + o];
  float4 sm = *(const float4*)&sum[o];
  float4 sq = *(const float4*)&sumsq[o];
  float4 gg = *(const float4*)&g[o];
  float4 bb = *(const float4*)&beta[o];
  const float inv = 1.0f / 4096.0f;
  float4 h;
  {
    float mean = sm.x * inv, var = sq.x * inv - mean * mean;
    h.x = fmaxf(gg.x * (y.x - mean) * rsqrtf(var + BN_EPS) + bb.x, 0.f);
  }
  {
    float mean = sm.y * inv, var = sq.y * inv - mean * mean;
    h.y = fmaxf(gg.y * (y.y - mean) * rsqrtf(var + BN_EPS) + bb.y, 0.f);
  }
  {
    float mean = sm.z * inv, var = sq.z * inv - mean * mean;
    h.z = fmaxf(gg.z * (y.z - mean) * rsqrtf(var + BN_EPS) + bb.z, 0.f);
  }
  {
    float mean = sm.w * inv, var = sq.w * inv - mean * mean;
    h.w = fmaxf(gg.w * (y.w - mean) * rsqrtf(var + BN_EPS) + bb.w, 0.f);
  }
  *(float4*)&out[((size_t)r * 16 + 15) * 512 + o] = h;
}

extern "C" void kernel_launch(void* const* d_in, const int* in_sizes, int n_in,
                              void* d_out, int out_size, void* d_ws, size_t ws_size,
                              hipStream_t stream) {
  const float* pf = (const float*)d_in[0];
  const float* bboxes = (const float*)d_in[1];
  const float* w1 = (const float*)d_in[2];
  const float* b1 = (const float*)d_in[3];
  const float* g1 = (const float*)d_in[4];
  const float* be1 = (const float*)d_in[5];
  const float* w2 = (const float*)d_in[6];
  const float* b2 = (const float*)d_in[7];
  const float* g2 = (const float*)d_in[8];
  const float* be2 = (const float*)d_in[9];
  float* out = (float*)d_out;

  // workspace layout (~13 MB)
  ushort* wb = (ushort*)d_ws;           // 524288 bf16 (w1|w2)
  ushort* Zb = wb + 524288;             // 2097152 bf16 (Z)
  float* Yb = (float*)(Zb + 2097152);   // 2097152 f32 (Y, reused both layers)
  float* stats = Yb + 2097152;          // 2048 f32: [sum1|sq1|sum2|sq2]
  float* sum1 = stats;
  float* sq1 = stats + 512;
  float* sum2 = stats + 1024;
  float* sq2 = stats + 1536;

  const float4* in4 = (const float4*)pf;
  float4* out4 = (float4*)out;

  // copy pool: 4096 (b,n) groups, t=15 rows never copied.
  // placement: gemm stages 1152 each (12.3KB LDS -> 13 blocks/CU),
  // norm stage 1792 (no LDS). Agg stages get NONE (their 51KB LDS would cap
  // copy occupancy at 3 blocks/CU -- the round-6 regression root cause).

  // S1: agg1 (X = pf[:, :, 15, :]) + weight prep + zero stats
  k_agg<<<256 + 256, 256, 0, stream>>>(pf + 7680, 8192, bboxes, stats,
                                       g1, be1, 0, Zb, w1, w2, wb, stats);
  // S2: gemm1 + copy[0,1152)
  k_gemm<<<512 + 1152, 256, 0, stream>>>(Zb, wb, b1, Yb, sum1, sq1,
                                         in4, out4, 0);
  // S3: agg2 (X = BN1(Yb) inline), pure compute
  k_agg<<<256, 256, 0, stream>>>(Yb, 512, bboxes, stats,
                                 g1, be1, 1, Zb, w1, w2, wb, stats);
  // S4: gemm2 + copy[1152,2304)
  k_gemm<<<512 + 1152, 256, 0, stream>>>(Zb, wb + 262144, b2, Yb, sum2, sq2,
                                         in4, out4, 1152);
  // S5: norm (t=15 slice) + copy[2304,4096) at full occupancy
  k_norm<<<2048 + 1792, 256, 0, stream>>>(Yb, sum2, sq2, g2, be2, out,
                                          in4, out4, 2304);
}

// Round 6
// 275.546 us; speedup vs baseline: 1.0701x; 1.0701x over previous
//
#include <hip/hip_runtime.h>
#include <hip/hip_bf16.h>

// GraphFeatureExtractor: B=64, N=64, T=16, D=512
// out = person_features with [:, :, 15, :] replaced by 2-layer ST-GCN result.
//
// Round 8: restore the best-measured configuration (round-2, 280.2us: copy
// spread evenly across ALL four compute stages -- placement experiments R4/R5
// that concentrated copy in "high-occupancy" stages were WORSE, 290/295us;
// Little's law shows even 3 blocks/CU sustains the per-CU BW share, so the
// LDS-occupancy theory was wrong and even spreading wins by keeping every
// stage's HBM pipe busy). One surgical change vs round-2:
//   - copy skips t=15 rows (norm overwrites them): slab blk covers rows
//     8blk..8blk+7; row%16==15 only occurs in ODD slabs at load/store r3 for
//     t>=128 -> predicate (blk even)||(t<128) is WAVE-UNIFORM (waves 0-1 vs
//     2-3). Saves 8MB read + 8MB write, no divergence.

typedef __attribute__((ext_vector_type(8))) short short8;
typedef __attribute__((ext_vector_type(4))) float v4f;

#define DIST_THRESH 150.0f
#define ROW_EPS 1e-6f
#define BN_EPS 1e-5f

__device__ __forceinline__ ushort f2bf(float f) {
  union { __hip_bfloat16 h; ushort u; } cv;
  cv.h = __float2bfloat16(f);
  return cv.u;
}

// dense bulk copy slab: 256 threads x 4 float4 = 16 KB = 8 rows of 512 floats.
// Slab blk covers rows 8blk..8blk+7; the t=15 row (row%16==15) appears only in
// odd slabs, covered by r3 for t>=128 -> wave-uniform skip, dense otherwise.
__device__ __forceinline__ void copy_slab(const float4* __restrict__ in,
                                          float4* __restrict__ out,
                                          int blk, int t) {
  size_t base = (size_t)blk * 1024 + t;
  bool keep = ((blk & 1) == 0) || (t < 128);  // wave-uniform (waves 0-1 true)
  float4 r0 = in[base];
  float4 r1 = in[base + 256];
  float4 r2 = in[base + 512];
  float4 r3;
  if (keep) r3 = in[base + 768];
  out[base] = r0;
  out[base + 256] = r1;
  out[base + 512] = r2;
  if (keep) out[base + 768] = r3;
}

// ---------------- aggregation (+inline adjacency, +optional BN/relu on X) ----
// Z[b][m][c] = sum_n A_norm[b][n][m] * X[b][n][c]
// block roles: [0,256) agg; [256,nonCopy) weight-prep (+zero stats);
//              [nonCopy, grid) dense copy slabs starting at copyBase.
__global__ __launch_bounds__(256) void k_agg(const float* __restrict__ Xbase,
                                             int rowStride,
                                             const float* __restrict__ bb,
                                             const float* __restrict__ stats,  // [sum(512)|sumsq(512)]
                                             const float* __restrict__ g,
                                             const float* __restrict__ beta,
                                             int applyBN,
                                             ushort* __restrict__ Z,
                                             const float4* __restrict__ in4,
                                             float4* __restrict__ out4,
                                             int copyBase,
                                             int nonCopy,
                                             const float* __restrict__ w1,
                                             const float* __restrict__ w2,
                                             ushort* __restrict__ wb,
                                             float* __restrict__ statsZ) {
  int id = blockIdx.x;
  int t = threadIdx.x;

  if (id >= nonCopy) {  // copy role (block-uniform branch, before any barrier)
    copy_slab(in4, out4, copyBase + (id - nonCopy), t);
    return;
  }
  if (id >= 256) {  // weight prep role (stage 1 only): 512 blocks, float4->4xbf16
    int i4 = (id - 256) * 256 + t;  // 0..131071
    float4 v = (i4 < 65536) ? *(const float4*)&w1[(size_t)i4 * 4]
                            : *(const float4*)&w2[(size_t)(i4 - 65536) * 4];
    ushort4 o;
    o.x = f2bf(v.x);
    o.y = f2bf(v.y);
    o.z = f2bf(v.z);
    o.w = f2bf(v.w);
    *(ushort4*)&wb[(size_t)i4 * 4] = o;
    if (i4 < 512) *(float4*)&statsZ[i4 * 4] = make_float4(0.f, 0.f, 0.f, 0.f);
    return;
  }

  int b = id >> 2;          // 64 batches
  int c0 = (id & 3) << 7;   // 4 column tiles of 128
  __shared__ float Xs[64][128];  // 32 KB
  __shared__ float As[64][64];   // 16 KB  (A_norm[b], [n][m])
  __shared__ float cxs[64], cys[64];
  __shared__ float scaleS[128], shiftS[128];
  __shared__ float rsum[64][4];
  __shared__ float invr[64];

  if (t < 64) {
    float4 v = *(const float4*)&bb[(size_t)(b * 64 + t) * 4];
    cxs[t] = v.x + 0.5f * v.z;
    cys[t] = v.y + 0.5f * v.w;
  }
  if (applyBN && t < 32) {
    int c = t * 4;  // local column in tile
    float4 sm = *(const float4*)&stats[c0 + c];
    float4 sq = *(const float4*)&stats[512 + c0 + c];
    float4 gg = *(const float4*)&g[c0 + c];
    float4 bt = *(const float4*)&beta[c0 + c];
    const float inv = 1.0f / 4096.0f;
    float mean, var, sc;
    mean = sm.x * inv; var = sq.x * inv - mean * mean; sc = gg.x * rsqrtf(var + BN_EPS);
    scaleS[c] = sc; shiftS[c] = bt.x - mean * sc;
    mean = sm.y * inv; var = sq.y * inv - mean * mean; sc = gg.y * rsqrtf(var + BN_EPS);
    scaleS[c + 1] = sc; shiftS[c + 1] = bt.y - mean * sc;
    mean = sm.z * inv; var = sq.z * inv - mean * mean; sc = gg.z * rsqrtf(var + BN_EPS);
    scaleS[c + 2] = sc; shiftS[c + 2] = bt.z - mean * sc;
    mean = sm.w * inv; var = sq.w * inv - mean * mean; sc = gg.w * rsqrtf(var + BN_EPS);
    scaleS[c + 3] = sc; shiftS[c + 3] = bt.w - mean * sc;
  }
  __syncthreads();

  // parallel adjacency: thread t owns row an = t>>2, 16-col segment aq = t&3
  int an = t >> 2, aq = t & 3;
  float av[16];
  {
    float mycx = cxs[an], mycy = cys[an];
    float ps = 0.f;
#pragma unroll
    for (int j = 0; j < 16; ++j) {
      int m = aq * 16 + j;
      float dx = mycx - cxs[m], dy = mycy - cys[m];
      float d = sqrtf(dx * dx + dy * dy);
      float a = (m == an) ? 1.0f : ((d < DIST_THRESH) ? 1.0f : 0.0f);
      av[j] = a;
      ps += a;
    }
    rsum[an][aq] = ps;
  }

  // X tile load (+BN/relu for layer 2) — overlapped with A-build
  const float* xb = Xbase + (size_t)b * 64 * rowStride;
  for (int i = t; i < 2048; i += 256) {  // 64 rows x 32 float4
    int n = i >> 5, c4 = (i & 31) << 2;
    float4 x = *(const float4*)&xb[(size_t)n * rowStride + c0 + c4];
    if (applyBN) {
      x.x = fmaxf(x.x * scaleS[c4] + shiftS[c4], 0.f);
      x.y = fmaxf(x.y * scaleS[c4 + 1] + shiftS[c4 + 1], 0.f);
      x.z = fmaxf(x.z * scaleS[c4 + 2] + shiftS[c4 + 2], 0.f);
      x.w = fmaxf(x.w * scaleS[c4 + 3] + shiftS[c4 + 3], 0.f);
    }
    *(float4*)&Xs[n][c4] = x;
  }
  __syncthreads();

  if (t < 64)
    invr[t] = 1.0f / (rsum[t][0] + rsum[t][1] + rsum[t][2] + rsum[t][3] + ROW_EPS);
  __syncthreads();

  {
    float iv = invr[an];
#pragma unroll
    for (int j = 0; j < 16; ++j) As[an][aq * 16 + j] = av[j] * iv;
  }
  __syncthreads();

  int c4 = (t & 31) << 2;   // column group (4 floats)
  int m0 = (t >> 5) << 3;   // 8 output nodes per thread
  float4 acc[8];
#pragma unroll
  for (int i = 0; i < 8; ++i) acc[i] = make_float4(0.f, 0.f, 0.f, 0.f);

  for (int n = 0; n < 64; ++n) {
    float4 x = *(const float4*)&Xs[n][c4];
    float4 a0 = *(const float4*)&As[n][m0];
    float4 a1 = *(const float4*)&As[n][m0 + 4];
    float as[8] = {a0.x, a0.y, a0.z, a0.w, a1.x, a1.y, a1.z, a1.w};
#pragma unroll
    for (int i = 0; i < 8; ++i) {
      acc[i].x = fmaf(as[i], x.x, acc[i].x);
      acc[i].y = fmaf(as[i], x.y, acc[i].y);
      acc[i].z = fmaf(as[i], x.z, acc[i].z);
      acc[i].w = fmaf(as[i], x.w, acc[i].w);
    }
  }

  size_t zbase = (size_t)b * 64 * 512 + c0 + c4;
#pragma unroll
  for (int i = 0; i < 8; ++i) {
    int m = m0 + i;
    ushort4 zz;
    zz.x = f2bf(acc[i].x);
    zz.y = f2bf(acc[i].y);
    zz.z = f2bf(acc[i].z);
    zz.w = f2bf(acc[i].w);
    *(ushort4*)&Z[zbase + (size_t)m * 512] = zz;
  }
}

// ---------------- GEMM: Y[r][o] = sum_c Z[r][c]*W[o][c] + bias[o] ------------
// tile 64(M) x 64(N), BK=32, 256 threads = 4 waves, each wave 16 rows x 64 cols
// block roles: [0,512) gemm; [512, grid) copy slabs starting at copyBase.
__global__ __launch_bounds__(256) void k_gemm(const ushort* __restrict__ Z,
                                              const ushort* __restrict__ W,
                                              const float* __restrict__ bias,
                                              float* __restrict__ Y,
                                              float* __restrict__ sum,
                                              float* __restrict__ sumsq,
                                              const float4* __restrict__ in4,
                                              float4* __restrict__ out4,
                                              int copyBase) {
  int id = blockIdx.x;
  int t = threadIdx.x;
  if (id >= 512) {  // copy role
    copy_slab(in4, out4, copyBase + (id - 512), t);
    return;
  }

  __shared__ __align__(16) ushort Zs[64 * 40];  // pad 32->40
  __shared__ __align__(16) ushort Ws[64 * 40];
  __shared__ float redS[4][64], redQ[4][64];

  int r0 = (id >> 3) << 6;  // 64 row tiles
  int o0 = (id & 7) << 6;   // 8 col tiles
  int wv = t >> 6, lane = t & 63;
  int m = lane & 15, q = lane >> 4;

  v4f acc[4];
#pragma unroll
  for (int nf = 0; nf < 4; ++nf) acc[nf] = (v4f){0.f, 0.f, 0.f, 0.f};

  int srow = t >> 2, scg = (t & 3) << 3;  // staging: row 0..63, 8-bf16 groups
  const ushort* zp = &Z[(size_t)(r0 + srow) * 512 + scg];
  const ushort* wp = &W[(size_t)(o0 + srow) * 512 + scg];

  // prefetch first tile
  uint4 zv = *(const uint4*)zp;
  uint4 wvv = *(const uint4*)wp;

  for (int ks = 0; ks < 16; ++ks) {
    __syncthreads();
    *(uint4*)&Zs[srow * 40 + scg] = zv;
    *(uint4*)&Ws[srow * 40 + scg] = wvv;
    __syncthreads();

    if (ks < 15) {  // prefetch next tile; latency hides under ds_read+MFMA
      zv = *(const uint4*)(zp + (ks + 1) * 32);
      wvv = *(const uint4*)(wp + (ks + 1) * 32);
    }

    short8 a = *(const short8*)&Zs[(wv * 16 + m) * 40 + q * 8];
#pragma unroll
    for (int nf = 0; nf < 4; ++nf) {
      short8 bfr = *(const short8*)&Ws[(nf * 16 + m) * 40 + q * 8];
      acc[nf] = __builtin_amdgcn_mfma_f32_16x16x32_bf16(a, bfr, acc[nf], 0, 0, 0);
    }
  }

  // epilogue: bias, store Y fp32, per-column BN partial sums
#pragma unroll
  for (int nf = 0; nf < 4; ++nf) {
    int col = o0 + nf * 16 + m;
    float bv = bias[col];
    float s = 0.f, s2 = 0.f;
#pragma unroll
    for (int reg = 0; reg < 4; ++reg) {
      int row = r0 + wv * 16 + q * 4 + reg;
      float y = acc[nf][reg] + bv;
      Y[(size_t)row * 512 + col] = y;
      s += y;
      s2 += y * y;
    }
    s += __shfl_xor(s, 16);
    s += __shfl_xor(s, 32);
    s2 += __shfl_xor(s2, 16);
    s2 += __shfl_xor(s2, 32);
    if (q == 0) {
      redS[wv][nf * 16 + m] = s;
      redQ[wv][nf * 16 + m] = s2;
    }
  }
  __syncthreads();
  if (t < 64) {
    float s = redS[0][t] + redS[1][t] + redS[2][t] + redS[3][t];
    float s2 = redQ[0][t] + redQ[1][t] + redQ[2][t] + redQ[3][t];
    atomicAdd(&sum[o0 + t], s);
    atomicAdd(&sumsq[o0 + t], s2);
  }
}

// ---------------- final BN + relu -> t=15 slice of d_out ----------------
__global__ __launch_bounds__(256) void k_norm(const float* __restrict__ Y,
                                              const float* __restrict__ sum,
                                              const float* __restrict__ sumsq,
                                              const float* __restrict__ g,
                                              const float* __restrict__ beta,
                                              float* __restrict__ out) {
  int idx = blockIdx.x * 256 + threadIdx.x;  // 524288 float4 groups
  int o = (idx & 127) << 2;
  int r = idx >> 7;
  float4 y = *(const float4*)&Y[(size_t)r * 512 + o];
  float4 sm = *(const float4*)&sum[o];
  float4 sq = *(const float4*)&sumsq[o];
  float4 gg = *(const float4*)&g[o];
  float4 bb = *(const float4*)&beta[o];
  const float inv = 1.0f / 4096.0f;
  float4 h;
  {
    float mean = sm.x * inv, var = sq.x * inv - mean * mean;
    h.x = fmaxf(gg.x * (y.x - mean) * rsqrtf(var + BN_EPS) + bb.x, 0.f);
  }
  {
    float mean = sm.y * inv, var = sq.y * inv - mean * mean;
    h.y = fmaxf(gg.y * (y.y - mean) * rsqrtf(var + BN_EPS) + bb.y, 0.f);
  }
  {
    float mean = sm.z * inv, var = sq.z * inv - mean * mean;
    h.z = fmaxf(gg.z * (y.z - mean) * rsqrtf(var + BN_EPS) + bb.z, 0.f);
  }
  {
    float mean = sm.w * inv, var = sq.w * inv - mean * mean;
    h.w = fmaxf(gg.w * (y.w - mean) * rsqrtf(var + BN_EPS) + bb.w, 0.f);
  }
  *(float4*)&out[((size_t)r * 16 + 15) * 512 + o] = h;
}

extern "C" void kernel_launch(void* const* d_in, const int* in_sizes, int n_in,
                              void* d_out, int out_size, void* d_ws, size_t ws_size,
                              hipStream_t stream) {
  const float* pf = (const float*)d_in[0];
  const float* bboxes = (const float*)d_in[1];
  const float* w1 = (const float*)d_in[2];
  const float* b1 = (const float*)d_in[3];
  const float* g1 = (const float*)d_in[4];
  const float* be1 = (const float*)d_in[5];
  const float* w2 = (const float*)d_in[6];
  const float* b2 = (const float*)d_in[7];
  const float* g2 = (const float*)d_in[8];
  const float* be2 = (const float*)d_in[9];
  float* out = (float*)d_out;

  // workspace layout (~13 MB)
  ushort* wb = (ushort*)d_ws;           // 524288 bf16 (w1|w2)
  ushort* Zb = wb + 524288;             // 2097152 bf16 (Z)
  float* Yb = (float*)(Zb + 2097152);   // 2097152 f32 (Y, reused both layers)
  float* stats = Yb + 2097152;          // 2048 f32: [sum1|sq1|sum2|sq2]
  float* sum1 = stats;
  float* sq1 = stats + 512;
  float* sum2 = stats + 1024;
  float* sq2 = stats + 1536;

  const float4* in4 = (const float4*)pf;
  float4* out4 = (float4*)out;

  // copy: 8192 slabs spread evenly across all four compute stages (round-2's
  // proven-best placement); t=15 rows never copied (norm writes them in S5).

  // S1: agg1 (X = pf[:, :, 15, :]) + weight prep + zero stats + copy[0,2048)
  k_agg<<<256 + 512 + 2048, 256, 0, stream>>>(pf + 7680, 8192, bboxes, stats,
                                              g1, be1, 0, Zb,
                                              in4, out4, 0, 768, w1, w2, wb, stats);
  // S2: gemm1 + copy[2048,4096)
  k_gemm<<<512 + 2048, 256, 0, stream>>>(Zb, wb, b1, Yb, sum1, sq1,
                                         in4, out4, 2048);
  // S3: agg2 (X = BN1(Yb) inline) + copy[4096,6144)
  k_agg<<<256 + 2048, 256, 0, stream>>>(Yb, 512, bboxes, stats,
                                        g1, be1, 1, Zb,
                                        in4, out4, 4096, 256, w1, w2, wb, stats);
  // S4: gemm2 + copy[6144,8192)
  k_gemm<<<512 + 2048, 256, 0, stream>>>(Zb, wb + 262144, b2, Yb, sum2, sq2,
                                         in4, out4, 6144);
  // S5: final BN -> out t=15 slice
  k_norm<<<2048, 256, 0, stream>>>(Yb, sum2, sq2, g2, be2, out);
}